// Round 3
// baseline (427.408 us; speedup 1.0000x reference)
//
#include <hip/hip_runtime.h>
#include <hip/hip_bf16.h>

// Rulebook sparse conv, R3: sort-then-reduce (no fp atomics).
//   R1/R2 showed the atomic scatter is op-rate bound (291G atomics/s ~= L2
//   ceiling). Replace with: counting-sort rules by out_idx (int atomics only),
//   GEMM writes vals[rule] bf16 rows coalesced, then a gather-reduce pass.
// Fallback to the R1 atomic kernel if ws_size is too small.

typedef __bf16 bf16x8_t __attribute__((ext_vector_type(8)));
typedef __bf16 bf16x2_t __attribute__((ext_vector_type(2)));
typedef float f32x4_t __attribute__((ext_vector_type(4)));

#define KOFF 27
#define RULES 50000
#define KR (KOFF * RULES) /* 1,350,000 */
#define CIN 64
#define COUT 64
#define NOUT 150000
#define BR 256
#define BPK ((RULES + BR - 1) / BR) /* 196 */

// ws layout (bytes, 256-aligned regions)
#define OFF_OFF 0u          /* int off[NOUT+1]: counts -> exclusive offsets */
#define OFF_CUR 600064u     /* int cursor[NOUT] */
#define OFF_BSUM 1200128u   /* int bsum[147] */
#define OFF_ORDER 1200384u  /* int order[KR] : sorted rule ids */
#define OFF_VALS 6600384u   /* bf16 vals[KR][64] */
#define WS_NEED (6600384ull + 172800000ull)

// ---------------- sort kernels ----------------
__global__ __launch_bounds__(256) void k_zero(int* __restrict__ cnt) {
  const int i = blockIdx.x * 256 + threadIdx.x;
  if (i < NOUT) cnt[i] = 0;
}

__global__ __launch_bounds__(256) void k_count(const int* __restrict__ out_idx,
                                               int* __restrict__ cnt) {
  const int i = blockIdx.x * 256 + threadIdx.x;
  if (i < KR) atomicAdd(&cnt[out_idx[i]], 1);
}

// block-level inclusive scan (1024 bins/block), in-place exclusive within block
__global__ __launch_bounds__(1024) void k_scan1(int* __restrict__ off,
                                                int* __restrict__ bsum) {
  __shared__ int s[1024];
  const int t = threadIdx.x;
  const int i = blockIdx.x * 1024 + t;
  const int v = (i < NOUT) ? off[i] : 0;
  s[t] = v;
  __syncthreads();
#pragma unroll
  for (int d = 1; d < 1024; d <<= 1) {
    const int u = (t >= d) ? s[t - d] : 0;
    __syncthreads();
    s[t] += u;
    __syncthreads();
  }
  if (i < NOUT) off[i] = s[t] - v;  // exclusive within block
  if (t == 1023) bsum[blockIdx.x] = s[1023];
}

__global__ __launch_bounds__(256) void k_scan2(int* __restrict__ bsum, int nb) {
  __shared__ int s[256];
  const int t = threadIdx.x;
  const int v = (t < nb) ? bsum[t] : 0;
  s[t] = v;
  __syncthreads();
#pragma unroll
  for (int d = 1; d < 256; d <<= 1) {
    const int u = (t >= d) ? s[t - d] : 0;
    __syncthreads();
    s[t] += u;
    __syncthreads();
  }
  if (t < nb) bsum[t] = s[t] - v;  // exclusive block offsets
}

__global__ __launch_bounds__(256) void k_scan3(int* __restrict__ off,
                                               int* __restrict__ cursor,
                                               const int* __restrict__ bsum) {
  const int i = blockIdx.x * 256 + threadIdx.x;
  if (i < NOUT) {
    const int v = off[i] + bsum[i >> 10];
    off[i] = v;
    cursor[i] = v;
  }
  if (i == 0) off[NOUT] = KR;
}

__global__ __launch_bounds__(256) void k_rank(const int* __restrict__ out_idx,
                                              int* __restrict__ cursor,
                                              int* __restrict__ order) {
  const int i = blockIdx.x * 256 + threadIdx.x;
  if (i < KR) {
    const int pos = atomicAdd(&cursor[out_idx[i]], 1);
    order[pos] = i;
  }
}

// ---------------- pass 1: grouped GEMM -> vals (bf16, rule-major) ----------------
__global__ __launch_bounds__(256) void pass1_kernel(
    const float* __restrict__ x, const float* __restrict__ w,
    const int* __restrict__ in_idx, __bf16* __restrict__ vals) {
  __shared__ char lds[256 * 128 + 64 * 128];
  char* const Abase = lds;
  char* const Bbase = lds + 256 * 128;

  const int bid = blockIdx.x;
  const int k = bid / BPK;
  const int rblk = bid - k * BPK;
  const int rule0 = rblk * BR;
  const int t = threadIdx.x;

  // stage A: gather 256 x-rows, f32->bf16, swizzled
  {
    const int chunk = t & 7;
    const int r0 = t >> 3;
#pragma unroll
    for (int pass = 0; pass < 8; ++pass) {
      const int r = r0 + pass * 32;
      const int rule = rule0 + r;
      bf16x8_t v;
      if (rule < RULES) {
        const int src = in_idx[(size_t)k * RULES + rule];
        const float* p = x + (size_t)src * CIN + chunk * 8;
        const float4 f0 = *reinterpret_cast<const float4*>(p);
        const float4 f1 = *reinterpret_cast<const float4*>(p + 4);
        v[0] = (__bf16)f0.x; v[1] = (__bf16)f0.y;
        v[2] = (__bf16)f0.z; v[3] = (__bf16)f0.w;
        v[4] = (__bf16)f1.x; v[5] = (__bf16)f1.y;
        v[6] = (__bf16)f1.z; v[7] = (__bf16)f1.w;
      } else {
#pragma unroll
        for (int e = 0; e < 8; ++e) v[e] = (__bf16)0.0f;
      }
      const int colByte = (chunk * 16) ^ ((r & 7) << 4);
      *reinterpret_cast<bf16x8_t*>(Abase + r * 128 + colByte) = v;
    }
  }

  // stage B: W_k^T -> LDS[o][c] bf16, swizzled
  {
    const int c = t >> 2;
    const int o0 = (t & 3) * 16;
    const float* wp = w + ((size_t)k * CIN + c) * COUT + o0;
#pragma unroll
    for (int j4 = 0; j4 < 4; ++j4) {
      const float4 f = *reinterpret_cast<const float4*>(wp + j4 * 4);
#pragma unroll
      for (int e = 0; e < 4; ++e) {
        const int o = o0 + j4 * 4 + e;
        const float val = (e == 0) ? f.x : (e == 1) ? f.y : (e == 2) ? f.z : f.w;
        const int addr = o * 128 + ((c * 2) ^ ((o & 7) << 4));
        *reinterpret_cast<__bf16*>(Bbase + addr) = (__bf16)val;
      }
    }
  }

  __syncthreads();

  const int wid = t >> 6;
  const int l = t & 63;
  const int rA = l & 15;
  const int g = l >> 4;

  bf16x8_t af[4][2];
  bf16x8_t bfr[4][2];
#pragma unroll
  for (int m = 0; m < 4; ++m)
#pragma unroll
    for (int kk = 0; kk < 2; ++kk) {
      const int r = wid * 64 + m * 16 + rA;
      const int colByte = (kk * 64 + g * 16) ^ ((r & 7) << 4);
      af[m][kk] = *reinterpret_cast<const bf16x8_t*>(Abase + r * 128 + colByte);
    }
#pragma unroll
  for (int n = 0; n < 4; ++n)
#pragma unroll
    for (int kk = 0; kk < 2; ++kk) {
      const int o = n * 16 + rA;
      const int colByte = (kk * 64 + g * 16) ^ ((o & 7) << 4);
      bfr[n][kk] = *reinterpret_cast<const bf16x8_t*>(Bbase + o * 128 + colByte);
    }

  __syncthreads();  // all frag reads done; LDS A reusable for D staging

  f32x4_t acc[4][4];
#pragma unroll
  for (int m = 0; m < 4; ++m)
#pragma unroll
    for (int n = 0; n < 4; ++n)
#pragma unroll
      for (int e = 0; e < 4; ++e) acc[m][n][e] = 0.0f;

#pragma unroll
  for (int kk = 0; kk < 2; ++kk)
#pragma unroll
    for (int m = 0; m < 4; ++m)
#pragma unroll
      for (int n = 0; n < 4; ++n)
        acc[m][n] = __builtin_amdgcn_mfma_f32_16x16x32_bf16(
            af[m][kk], bfr[n][kk], acc[m][n], 0, 0, 0);

  // stage D -> LDS bf16 rows (swizzled). D: row=wid*64+m*16+g*4+j, col=n*16+rA.
  const bool evenLane = (rA & 1) == 0;
#pragma unroll
  for (int m = 0; m < 4; ++m) {
#pragma unroll
    for (int j = 0; j < 4; ++j) {
      const int rr = wid * 64 + m * 16 + g * 4 + j;
      float mine[4], other[4];
#pragma unroll
      for (int n = 0; n < 4; ++n) {
        mine[n] = acc[m][n][j];
        other[n] = __shfl_xor(mine[n], 1, 64);
      }
      const int swz = (rr & 7) << 4;
      if (evenLane) {
#pragma unroll
        for (int n = 0; n < 2; ++n) {
          bf16x2_t p; p[0] = (__bf16)mine[n]; p[1] = (__bf16)other[n];
          const int col = n * 16 + rA;
          *reinterpret_cast<bf16x2_t*>(Abase + rr * 128 + ((col * 2) ^ swz)) = p;
        }
      } else {
#pragma unroll
        for (int n = 2; n < 4; ++n) {
          bf16x2_t p; p[0] = (__bf16)other[n]; p[1] = (__bf16)mine[n];
          const int col = n * 16 + rA - 1;
          *reinterpret_cast<bf16x2_t*>(Abase + rr * 128 + ((col * 2) ^ swz)) = p;
        }
      }
    }
  }

  __syncthreads();

  // writeback: contiguous bf16 rows to vals[(k*RULES+rule)*64]
  {
    const int chunk = t & 7;
    const int r0 = t >> 3;
    __bf16* const base = vals + (size_t)(k * RULES + rule0) * COUT;
#pragma unroll
    for (int pass = 0; pass < 8; ++pass) {
      const int r = r0 + pass * 32;
      if (rule0 + r < RULES) {
        const bf16x8_t v = *reinterpret_cast<const bf16x8_t*>(
            Abase + r * 128 + ((chunk * 16) ^ ((r & 7) << 4)));
        *reinterpret_cast<bf16x8_t*>(base + r * 64 + chunk * 8) = v;
      }
    }
  }
}

// ---------------- pass 2: gather-reduce per out row ----------------
__global__ __launch_bounds__(256) void pass2_kernel(
    const __bf16* __restrict__ vals, const int* __restrict__ order,
    const int* __restrict__ off, const float* __restrict__ bias,
    float* __restrict__ out) {
  const int t = threadIdx.x;
  const int sub = t & 3;               // channel quarter
  const int o = blockIdx.x * 64 + (t >> 2);
  if (o >= NOUT) return;

  float acc[16];
  {
    const float4 b0 = reinterpret_cast<const float4*>(bias)[sub * 4 + 0];
    const float4 b1 = reinterpret_cast<const float4*>(bias)[sub * 4 + 1];
    const float4 b2 = reinterpret_cast<const float4*>(bias)[sub * 4 + 2];
    const float4 b3 = reinterpret_cast<const float4*>(bias)[sub * 4 + 3];
    acc[0] = b0.x; acc[1] = b0.y; acc[2] = b0.z; acc[3] = b0.w;
    acc[4] = b1.x; acc[5] = b1.y; acc[6] = b1.z; acc[7] = b1.w;
    acc[8] = b2.x; acc[9] = b2.y; acc[10] = b2.z; acc[11] = b2.w;
    acc[12] = b3.x; acc[13] = b3.y; acc[14] = b3.z; acc[15] = b3.w;
  }

  const int r0 = off[o];
  const int r1 = off[o + 1];
  for (int j = r0; j < r1; ++j) {
    const int rid = order[j];
    const __bf16* vp = vals + (size_t)rid * COUT + sub * 16;
    const bf16x8_t v0 = *reinterpret_cast<const bf16x8_t*>(vp);
    const bf16x8_t v1 = *reinterpret_cast<const bf16x8_t*>(vp + 8);
#pragma unroll
    for (int e = 0; e < 8; ++e) {
      acc[e] += (float)v0[e];
      acc[8 + e] += (float)v1[e];
    }
  }

  float* op = out + (size_t)o * COUT + sub * 16;
  reinterpret_cast<float4*>(op)[0] = make_float4(acc[0], acc[1], acc[2], acc[3]);
  reinterpret_cast<float4*>(op)[1] = make_float4(acc[4], acc[5], acc[6], acc[7]);
  reinterpret_cast<float4*>(op)[2] = make_float4(acc[8], acc[9], acc[10], acc[11]);
  reinterpret_cast<float4*>(op)[3] = make_float4(acc[12], acc[13], acc[14], acc[15]);
}

// ---------------- fallback (R1): atomic scatter ----------------
__global__ __launch_bounds__(256) void init_out_kernel(
    const float* __restrict__ bias, float* __restrict__ out, int total4) {
  const int i = blockIdx.x * blockDim.x + threadIdx.x;
  if (i < total4) {
    const float4 v = reinterpret_cast<const float4*>(bias)[i & 15];
    reinterpret_cast<float4*>(out)[i] = v;
  }
}

__global__ __launch_bounds__(256) void spconv_atomic_kernel(
    const float* __restrict__ x, const float* __restrict__ w,
    const int* __restrict__ in_idx, const int* __restrict__ out_idx,
    float* __restrict__ out) {
  __shared__ char lds[256 * 128 + 64 * 128];
  char* const Abase = lds;
  char* const Bbase = lds + 256 * 128;

  const int bid = blockIdx.x;
  const int k = bid / BPK;
  const int rblk = bid - k * BPK;
  const int rule0 = rblk * BR;
  const int t = threadIdx.x;

  {
    const int chunk = t & 7;
    const int r0 = t >> 3;
#pragma unroll
    for (int pass = 0; pass < 8; ++pass) {
      const int r = r0 + pass * 32;
      const int rule = rule0 + r;
      bf16x8_t v;
      if (rule < RULES) {
        const int src = in_idx[(size_t)k * RULES + rule];
        const float* p = x + (size_t)src * CIN + chunk * 8;
        const float4 f0 = *reinterpret_cast<const float4*>(p);
        const float4 f1 = *reinterpret_cast<const float4*>(p + 4);
        v[0] = (__bf16)f0.x; v[1] = (__bf16)f0.y;
        v[2] = (__bf16)f0.z; v[3] = (__bf16)f0.w;
        v[4] = (__bf16)f1.x; v[5] = (__bf16)f1.y;
        v[6] = (__bf16)f1.z; v[7] = (__bf16)f1.w;
      } else {
#pragma unroll
        for (int e = 0; e < 8; ++e) v[e] = (__bf16)0.0f;
      }
      const int colByte = (chunk * 16) ^ ((r & 7) << 4);
      *reinterpret_cast<bf16x8_t*>(Abase + r * 128 + colByte) = v;
    }
  }
  {
    const int c = t >> 2;
    const int o0 = (t & 3) * 16;
    const float* wp = w + ((size_t)k * CIN + c) * COUT + o0;
#pragma unroll
    for (int j4 = 0; j4 < 4; ++j4) {
      const float4 f = *reinterpret_cast<const float4*>(wp + j4 * 4);
#pragma unroll
      for (int e = 0; e < 4; ++e) {
        const int o = o0 + j4 * 4 + e;
        const float val = (e == 0) ? f.x : (e == 1) ? f.y : (e == 2) ? f.z : f.w;
        const int addr = o * 128 + ((c * 2) ^ ((o & 7) << 4));
        *reinterpret_cast<__bf16*>(Bbase + addr) = (__bf16)val;
      }
    }
  }
  __syncthreads();

  const int wid = t >> 6;
  const int l = t & 63;
  const int rA = l & 15;
  const int g = l >> 4;

  bf16x8_t af[4][2];
  bf16x8_t bfr[4][2];
#pragma unroll
  for (int m = 0; m < 4; ++m)
#pragma unroll
    for (int kk = 0; kk < 2; ++kk) {
      const int r = wid * 64 + m * 16 + rA;
      const int colByte = (kk * 64 + g * 16) ^ ((r & 7) << 4);
      af[m][kk] = *reinterpret_cast<const bf16x8_t*>(Abase + r * 128 + colByte);
    }
#pragma unroll
  for (int n = 0; n < 4; ++n)
#pragma unroll
    for (int kk = 0; kk < 2; ++kk) {
      const int o = n * 16 + rA;
      const int colByte = (kk * 64 + g * 16) ^ ((o & 7) << 4);
      bfr[n][kk] = *reinterpret_cast<const bf16x8_t*>(Bbase + o * 128 + colByte);
    }

  f32x4_t acc[4][4];
#pragma unroll
  for (int m = 0; m < 4; ++m)
#pragma unroll
    for (int n = 0; n < 4; ++n)
#pragma unroll
      for (int e = 0; e < 4; ++e) acc[m][n][e] = 0.0f;

#pragma unroll
  for (int kk = 0; kk < 2; ++kk)
#pragma unroll
    for (int m = 0; m < 4; ++m)
#pragma unroll
      for (int n = 0; n < 4; ++n)
        acc[m][n] = __builtin_amdgcn_mfma_f32_16x16x32_bf16(
            af[m][kk], bfr[n][kk], acc[m][n], 0, 0, 0);

#pragma unroll
  for (int m = 0; m < 4; ++m)
#pragma unroll
    for (int j = 0; j < 4; ++j) {
      const int rr = wid * 64 + m * 16 + g * 4 + j;
      const int rule = rule0 + rr;
      if (rule < RULES) {
        const int orow = out_idx[(size_t)k * RULES + rule];
        float* op = out + (size_t)orow * COUT + rA;
#pragma unroll
        for (int n = 0; n < 4; ++n) atomicAdd(op + n * 16, acc[m][n][j]);
      }
    }
}

// ---------------- launch ----------------
extern "C" void kernel_launch(void* const* d_in, const int* in_sizes, int n_in,
                              void* d_out, int out_size, void* d_ws, size_t ws_size,
                              hipStream_t stream) {
  const float* x = (const float*)d_in[0];
  const float* w = (const float*)d_in[1];
  const float* bias = (const float*)d_in[2];
  const int* in_idx = (const int*)d_in[3];
  const int* out_idx = (const int*)d_in[4];
  float* out = (float*)d_out;

  if (ws_size >= WS_NEED) {
    char* ws = (char*)d_ws;
    int* off = (int*)(ws + OFF_OFF);
    int* cursor = (int*)(ws + OFF_CUR);
    int* bsum = (int*)(ws + OFF_BSUM);
    int* order = (int*)(ws + OFF_ORDER);
    __bf16* vals = (__bf16*)(ws + OFF_VALS);

    const int nb1 = (NOUT + 1023) / 1024;  // 147
    pass1_kernel<<<KOFF * BPK, 256, 0, stream>>>(x, w, in_idx, vals);
    k_zero<<<(NOUT + 255) / 256, 256, 0, stream>>>(off);
    k_count<<<(KR + 255) / 256, 256, 0, stream>>>(out_idx, off);
    k_scan1<<<nb1, 1024, 0, stream>>>(off, bsum);
    k_scan2<<<1, 256, 0, stream>>>(bsum, nb1);
    k_scan3<<<(NOUT + 255) / 256, 256, 0, stream>>>(off, cursor, bsum);
    k_rank<<<(KR + 255) / 256, 256, 0, stream>>>(out_idx, cursor, order);
    pass2_kernel<<<(NOUT + 63) / 64, 256, 0, stream>>>(vals, order, off, bias, out);
  } else {
    const int total4 = NOUT * COUT / 4;
    init_out_kernel<<<(total4 + 255) / 256, 256, 0, stream>>>(bias, out, total4);
    spconv_atomic_kernel<<<KOFF * BPK, 256, 0, stream>>>(x, w, in_idx, out_idx, out);
  }
}

// Round 4
// 364.964 us; speedup vs baseline: 1.1711x; 1.1711x over previous
//
#include <hip/hip_runtime.h>
#include <hip/hip_bf16.h>

// Rulebook sparse conv, R4: sort-then-reduce with NO scattered dwords.
//   R3 lesson: order[pos]=i scattered-dword writes cost 114us (94MB partial
//   lines). Fix: rank[i] written coalesced; pass1 scatters full 128B val rows
//   directly into sorted position; pass2 is a streaming segment reduce.

typedef __bf16 bf16x8_t __attribute__((ext_vector_type(8)));
typedef __bf16 bf16x2_t __attribute__((ext_vector_type(2)));
typedef float f32x4_t __attribute__((ext_vector_type(4)));

#define KOFF 27
#define RULES 50000
#define KR (KOFF * RULES) /* 1,350,000 */
#define CIN 64
#define COUT 64
#define NOUT 150000
#define BR 256
#define BPK ((RULES + BR - 1) / BR) /* 196 */

// ws layout (bytes)
#define OFF_OFF 0u          /* int off[NOUT+1] */
#define OFF_CUR 600064u     /* int cursor[NOUT] */
#define OFF_BSUM 1200128u   /* int bsum[147] */
#define OFF_RANK 1200896u   /* int rank[KR] */
#define OFF_VALS 6600960u   /* bf16 vals[KR][64] (sorted by out row) */
#define WS_NEED (6600960ull + 172800000ull)

// ---------------- sort kernels ----------------
__global__ __launch_bounds__(256) void k_zero(int* __restrict__ cnt) {
  const int i = blockIdx.x * 256 + threadIdx.x;
  if (i < NOUT) cnt[i] = 0;
}

__global__ __launch_bounds__(256) void k_count(const int* __restrict__ out_idx,
                                               int* __restrict__ cnt) {
  const int i = blockIdx.x * 256 + threadIdx.x;
  if (i < KR / 4) {
    const int4 v = reinterpret_cast<const int4*>(out_idx)[i];
    atomicAdd(&cnt[v.x], 1);
    atomicAdd(&cnt[v.y], 1);
    atomicAdd(&cnt[v.z], 1);
    atomicAdd(&cnt[v.w], 1);
  }
}

__global__ __launch_bounds__(1024) void k_scan1(int* __restrict__ off,
                                                int* __restrict__ bsum) {
  __shared__ int s[1024];
  const int t = threadIdx.x;
  const int i = blockIdx.x * 1024 + t;
  const int v = (i < NOUT) ? off[i] : 0;
  s[t] = v;
  __syncthreads();
#pragma unroll
  for (int d = 1; d < 1024; d <<= 1) {
    const int u = (t >= d) ? s[t - d] : 0;
    __syncthreads();
    s[t] += u;
    __syncthreads();
  }
  if (i < NOUT) off[i] = s[t] - v;  // exclusive within block
  if (t == 1023) bsum[blockIdx.x] = s[1023];
}

__global__ __launch_bounds__(256) void k_scan2(int* __restrict__ bsum, int nb) {
  __shared__ int s[256];
  const int t = threadIdx.x;
  const int v = (t < nb) ? bsum[t] : 0;
  s[t] = v;
  __syncthreads();
#pragma unroll
  for (int d = 1; d < 256; d <<= 1) {
    const int u = (t >= d) ? s[t - d] : 0;
    __syncthreads();
    s[t] += u;
    __syncthreads();
  }
  if (t < nb) bsum[t] = s[t] - v;
}

__global__ __launch_bounds__(256) void k_scan3(int* __restrict__ off,
                                               int* __restrict__ cursor,
                                               const int* __restrict__ bsum) {
  const int i = blockIdx.x * 256 + threadIdx.x;
  if (i < NOUT) {
    const int v = off[i] + bsum[i >> 10];
    off[i] = v;
    cursor[i] = v;
  }
  if (i == 0) off[NOUT] = KR;
}

// rank[i] = position of rule i within its out-row segment (coalesced write)
__global__ __launch_bounds__(256) void k_rank2(const int* __restrict__ out_idx,
                                               int* __restrict__ cursor,
                                               int* __restrict__ rank) {
  const int i = blockIdx.x * 256 + threadIdx.x;
  if (i < KR) rank[i] = atomicAdd(&cursor[out_idx[i]], 1);
}

// ---------------- pass 1: grouped GEMM, scatter 128B rows to sorted slots ----
__global__ __launch_bounds__(256) void pass1_kernel(
    const float* __restrict__ x, const float* __restrict__ w,
    const int* __restrict__ in_idx, const int* __restrict__ rank,
    __bf16* __restrict__ vals) {
  __shared__ char lds[256 * 128 + 64 * 128];
  char* const Abase = lds;
  char* const Bbase = lds + 256 * 128;

  const int bid = blockIdx.x;
  const int k = bid / BPK;
  const int rblk = bid - k * BPK;
  const int rule0 = rblk * BR;
  const int t = threadIdx.x;

  // stage A: gather 256 x-rows, f32->bf16, swizzled
  {
    const int chunk = t & 7;
    const int r0 = t >> 3;
#pragma unroll
    for (int pass = 0; pass < 8; ++pass) {
      const int r = r0 + pass * 32;
      const int rule = rule0 + r;
      bf16x8_t v;
      if (rule < RULES) {
        const int src = in_idx[(size_t)k * RULES + rule];
        const float* p = x + (size_t)src * CIN + chunk * 8;
        const float4 f0 = *reinterpret_cast<const float4*>(p);
        const float4 f1 = *reinterpret_cast<const float4*>(p + 4);
        v[0] = (__bf16)f0.x; v[1] = (__bf16)f0.y;
        v[2] = (__bf16)f0.z; v[3] = (__bf16)f0.w;
        v[4] = (__bf16)f1.x; v[5] = (__bf16)f1.y;
        v[6] = (__bf16)f1.z; v[7] = (__bf16)f1.w;
      } else {
#pragma unroll
        for (int e = 0; e < 8; ++e) v[e] = (__bf16)0.0f;
      }
      const int colByte = (chunk * 16) ^ ((r & 7) << 4);
      *reinterpret_cast<bf16x8_t*>(Abase + r * 128 + colByte) = v;
    }
  }

  // stage B: W_k^T -> LDS[o][c] bf16, swizzled
  {
    const int c = t >> 2;
    const int o0 = (t & 3) * 16;
    const float* wp = w + ((size_t)k * CIN + c) * COUT + o0;
#pragma unroll
    for (int j4 = 0; j4 < 4; ++j4) {
      const float4 f = *reinterpret_cast<const float4*>(wp + j4 * 4);
#pragma unroll
      for (int e = 0; e < 4; ++e) {
        const int o = o0 + j4 * 4 + e;
        const float val = (e == 0) ? f.x : (e == 1) ? f.y : (e == 2) ? f.z : f.w;
        const int addr = o * 128 + ((c * 2) ^ ((o & 7) << 4));
        *reinterpret_cast<__bf16*>(Bbase + addr) = (__bf16)val;
      }
    }
  }

  __syncthreads();

  const int wid = t >> 6;
  const int l = t & 63;
  const int rA = l & 15;
  const int g = l >> 4;

  bf16x8_t af[4][2];
  bf16x8_t bfr[4][2];
#pragma unroll
  for (int m = 0; m < 4; ++m)
#pragma unroll
    for (int kk = 0; kk < 2; ++kk) {
      const int r = wid * 64 + m * 16 + rA;
      const int colByte = (kk * 64 + g * 16) ^ ((r & 7) << 4);
      af[m][kk] = *reinterpret_cast<const bf16x8_t*>(Abase + r * 128 + colByte);
    }
#pragma unroll
  for (int n = 0; n < 4; ++n)
#pragma unroll
    for (int kk = 0; kk < 2; ++kk) {
      const int o = n * 16 + rA;
      const int colByte = (kk * 64 + g * 16) ^ ((o & 7) << 4);
      bfr[n][kk] = *reinterpret_cast<const bf16x8_t*>(Bbase + o * 128 + colByte);
    }

  __syncthreads();  // frag reads done; Abase reused for D staging

  f32x4_t acc[4][4];
#pragma unroll
  for (int m = 0; m < 4; ++m)
#pragma unroll
    for (int n = 0; n < 4; ++n)
#pragma unroll
      for (int e = 0; e < 4; ++e) acc[m][n][e] = 0.0f;

#pragma unroll
  for (int kk = 0; kk < 2; ++kk)
#pragma unroll
    for (int m = 0; m < 4; ++m)
#pragma unroll
      for (int n = 0; n < 4; ++n)
        acc[m][n] = __builtin_amdgcn_mfma_f32_16x16x32_bf16(
            af[m][kk], bfr[n][kk], acc[m][n], 0, 0, 0);

  // stage D -> LDS bf16 rows (swizzled)
  const bool evenLane = (rA & 1) == 0;
#pragma unroll
  for (int m = 0; m < 4; ++m) {
#pragma unroll
    for (int j = 0; j < 4; ++j) {
      const int rr = wid * 64 + m * 16 + g * 4 + j;
      float mine[4], other[4];
#pragma unroll
      for (int n = 0; n < 4; ++n) {
        mine[n] = acc[m][n][j];
        other[n] = __shfl_xor(mine[n], 1, 64);
      }
      const int swz = (rr & 7) << 4;
      if (evenLane) {
#pragma unroll
        for (int n = 0; n < 2; ++n) {
          bf16x2_t p; p[0] = (__bf16)mine[n]; p[1] = (__bf16)other[n];
          const int col = n * 16 + rA;
          *reinterpret_cast<bf16x2_t*>(Abase + rr * 128 + ((col * 2) ^ swz)) = p;
        }
      } else {
#pragma unroll
        for (int n = 2; n < 4; ++n) {
          bf16x2_t p; p[0] = (__bf16)other[n]; p[1] = (__bf16)mine[n];
          const int col = n * 16 + rA - 1;
          *reinterpret_cast<bf16x2_t*>(Abase + rr * 128 + ((col * 2) ^ swz)) = p;
        }
      }
    }
  }

  __syncthreads();

  // writeback: scatter full 128B rows to vals[rank[rule]]
  {
    const int chunk = t & 7;
    const int r0 = t >> 3;
#pragma unroll
    for (int pass = 0; pass < 8; ++pass) {
      const int r = r0 + pass * 32;
      const int rule = rule0 + r;
      if (rule < RULES) {
        const int dst = rank[(size_t)k * RULES + rule];
        const bf16x8_t v = *reinterpret_cast<const bf16x8_t*>(
            Abase + r * 128 + ((chunk * 16) ^ ((r & 7) << 4)));
        *reinterpret_cast<bf16x8_t*>(vals + (size_t)dst * COUT + chunk * 8) = v;
      }
    }
  }
}

// ---------------- pass 2: streaming segment reduce ----------------
__global__ __launch_bounds__(256) void pass2_kernel(
    const __bf16* __restrict__ vals, const int* __restrict__ off,
    const float* __restrict__ bias, float* __restrict__ out) {
  const int t = threadIdx.x;
  const int sub = t & 3;               // channel quarter (16 ch)
  const int o = blockIdx.x * 64 + (t >> 2);
  if (o >= NOUT) return;

  float acc[16];
  {
    const float4 b0 = reinterpret_cast<const float4*>(bias)[sub * 4 + 0];
    const float4 b1 = reinterpret_cast<const float4*>(bias)[sub * 4 + 1];
    const float4 b2 = reinterpret_cast<const float4*>(bias)[sub * 4 + 2];
    const float4 b3 = reinterpret_cast<const float4*>(bias)[sub * 4 + 3];
    acc[0] = b0.x; acc[1] = b0.y; acc[2] = b0.z; acc[3] = b0.w;
    acc[4] = b1.x; acc[5] = b1.y; acc[6] = b1.z; acc[7] = b1.w;
    acc[8] = b2.x; acc[9] = b2.y; acc[10] = b2.z; acc[11] = b2.w;
    acc[12] = b3.x; acc[13] = b3.y; acc[14] = b3.z; acc[15] = b3.w;
  }

  const int r0 = off[o];
  const int r1 = off[o + 1];
  for (int j = r0; j < r1; ++j) {
    const __bf16* vp = vals + (size_t)j * COUT + sub * 16;
    const bf16x8_t v0 = *reinterpret_cast<const bf16x8_t*>(vp);
    const bf16x8_t v1 = *reinterpret_cast<const bf16x8_t*>(vp + 8);
#pragma unroll
    for (int e = 0; e < 8; ++e) {
      acc[e] += (float)v0[e];
      acc[8 + e] += (float)v1[e];
    }
  }

  float* op = out + (size_t)o * COUT + sub * 16;
  reinterpret_cast<float4*>(op)[0] = make_float4(acc[0], acc[1], acc[2], acc[3]);
  reinterpret_cast<float4*>(op)[1] = make_float4(acc[4], acc[5], acc[6], acc[7]);
  reinterpret_cast<float4*>(op)[2] = make_float4(acc[8], acc[9], acc[10], acc[11]);
  reinterpret_cast<float4*>(op)[3] = make_float4(acc[12], acc[13], acc[14], acc[15]);
}

// ---------------- fallback (R1): atomic scatter ----------------
__global__ __launch_bounds__(256) void init_out_kernel(
    const float* __restrict__ bias, float* __restrict__ out, int total4) {
  const int i = blockIdx.x * blockDim.x + threadIdx.x;
  if (i < total4) {
    const float4 v = reinterpret_cast<const float4*>(bias)[i & 15];
    reinterpret_cast<float4*>(out)[i] = v;
  }
}

__global__ __launch_bounds__(256) void spconv_atomic_kernel(
    const float* __restrict__ x, const float* __restrict__ w,
    const int* __restrict__ in_idx, const int* __restrict__ out_idx,
    float* __restrict__ out) {
  __shared__ char lds[256 * 128 + 64 * 128];
  char* const Abase = lds;
  char* const Bbase = lds + 256 * 128;

  const int bid = blockIdx.x;
  const int k = bid / BPK;
  const int rblk = bid - k * BPK;
  const int rule0 = rblk * BR;
  const int t = threadIdx.x;

  {
    const int chunk = t & 7;
    const int r0 = t >> 3;
#pragma unroll
    for (int pass = 0; pass < 8; ++pass) {
      const int r = r0 + pass * 32;
      const int rule = rule0 + r;
      bf16x8_t v;
      if (rule < RULES) {
        const int src = in_idx[(size_t)k * RULES + rule];
        const float* p = x + (size_t)src * CIN + chunk * 8;
        const float4 f0 = *reinterpret_cast<const float4*>(p);
        const float4 f1 = *reinterpret_cast<const float4*>(p + 4);
        v[0] = (__bf16)f0.x; v[1] = (__bf16)f0.y;
        v[2] = (__bf16)f0.z; v[3] = (__bf16)f0.w;
        v[4] = (__bf16)f1.x; v[5] = (__bf16)f1.y;
        v[6] = (__bf16)f1.z; v[7] = (__bf16)f1.w;
      } else {
#pragma unroll
        for (int e = 0; e < 8; ++e) v[e] = (__bf16)0.0f;
      }
      const int colByte = (chunk * 16) ^ ((r & 7) << 4);
      *reinterpret_cast<bf16x8_t*>(Abase + r * 128 + colByte) = v;
    }
  }
  {
    const int c = t >> 2;
    const int o0 = (t & 3) * 16;
    const float* wp = w + ((size_t)k * CIN + c) * COUT + o0;
#pragma unroll
    for (int j4 = 0; j4 < 4; ++j4) {
      const float4 f = *reinterpret_cast<const float4*>(wp + j4 * 4);
#pragma unroll
      for (int e = 0; e < 4; ++e) {
        const int o = o0 + j4 * 4 + e;
        const float val = (e == 0) ? f.x : (e == 1) ? f.y : (e == 2) ? f.z : f.w;
        const int addr = o * 128 + ((c * 2) ^ ((o & 7) << 4));
        *reinterpret_cast<__bf16*>(Bbase + addr) = (__bf16)val;
      }
    }
  }
  __syncthreads();

  const int wid = t >> 6;
  const int l = t & 63;
  const int rA = l & 15;
  const int g = l >> 4;

  bf16x8_t af[4][2];
  bf16x8_t bfr[4][2];
#pragma unroll
  for (int m = 0; m < 4; ++m)
#pragma unroll
    for (int kk = 0; kk < 2; ++kk) {
      const int r = wid * 64 + m * 16 + rA;
      const int colByte = (kk * 64 + g * 16) ^ ((r & 7) << 4);
      af[m][kk] = *reinterpret_cast<const bf16x8_t*>(Abase + r * 128 + colByte);
    }
#pragma unroll
  for (int n = 0; n < 4; ++n)
#pragma unroll
    for (int kk = 0; kk < 2; ++kk) {
      const int o = n * 16 + rA;
      const int colByte = (kk * 64 + g * 16) ^ ((o & 7) << 4);
      bfr[n][kk] = *reinterpret_cast<const bf16x8_t*>(Bbase + o * 128 + colByte);
    }

  f32x4_t acc[4][4];
#pragma unroll
  for (int m = 0; m < 4; ++m)
#pragma unroll
    for (int n = 0; n < 4; ++n)
#pragma unroll
      for (int e = 0; e < 4; ++e) acc[m][n][e] = 0.0f;

#pragma unroll
  for (int kk = 0; kk < 2; ++kk)
#pragma unroll
    for (int m = 0; m < 4; ++m)
#pragma unroll
      for (int n = 0; n < 4; ++n)
        acc[m][n] = __builtin_amdgcn_mfma_f32_16x16x32_bf16(
            af[m][kk], bfr[n][kk], acc[m][n], 0, 0, 0);

#pragma unroll
  for (int m = 0; m < 4; ++m)
#pragma unroll
    for (int j = 0; j < 4; ++j) {
      const int rr = wid * 64 + m * 16 + g * 4 + j;
      const int rule = rule0 + rr;
      if (rule < RULES) {
        const int orow = out_idx[(size_t)k * RULES + rule];
        float* op = out + (size_t)orow * COUT + rA;
#pragma unroll
        for (int n = 0; n < 4; ++n) atomicAdd(op + n * 16, acc[m][n][j]);
      }
    }
}

// ---------------- launch ----------------
extern "C" void kernel_launch(void* const* d_in, const int* in_sizes, int n_in,
                              void* d_out, int out_size, void* d_ws, size_t ws_size,
                              hipStream_t stream) {
  const float* x = (const float*)d_in[0];
  const float* w = (const float*)d_in[1];
  const float* bias = (const float*)d_in[2];
  const int* in_idx = (const int*)d_in[3];
  const int* out_idx = (const int*)d_in[4];
  float* out = (float*)d_out;

  if (ws_size >= WS_NEED) {
    char* ws = (char*)d_ws;
    int* off = (int*)(ws + OFF_OFF);
    int* cursor = (int*)(ws + OFF_CUR);
    int* bsum = (int*)(ws + OFF_BSUM);
    int* rank = (int*)(ws + OFF_RANK);
    __bf16* vals = (__bf16*)(ws + OFF_VALS);

    const int nb1 = (NOUT + 1023) / 1024;  // 147
    k_zero<<<(NOUT + 255) / 256, 256, 0, stream>>>(off);
    k_count<<<(KR / 4 + 255) / 256, 256, 0, stream>>>(out_idx, off);
    k_scan1<<<nb1, 1024, 0, stream>>>(off, bsum);
    k_scan2<<<1, 256, 0, stream>>>(bsum, nb1);
    k_scan3<<<(NOUT + 255) / 256, 256, 0, stream>>>(off, cursor, bsum);
    k_rank2<<<(KR + 255) / 256, 256, 0, stream>>>(out_idx, cursor, rank);
    pass1_kernel<<<KOFF * BPK, 256, 0, stream>>>(x, w, in_idx, rank, vals);
    pass2_kernel<<<(NOUT + 63) / 64, 256, 0, stream>>>(vals, off, bias, out);
  } else {
    const int total4 = NOUT * COUT / 4;
    init_out_kernel<<<(total4 + 255) / 256, 256, 0, stream>>>(bias, out, total4);
    spconv_atomic_kernel<<<KOFF * BPK, 256, 0, stream>>>(x, w, in_idx, out_idx, out);
  }
}

// Round 5
// 325.855 us; speedup vs baseline: 1.3117x; 1.1200x over previous
//
#include <hip/hip_runtime.h>
#include <hip/hip_bf16.h>

// Rulebook sparse conv, R5.
//   - x pre-converted to bf16 table xb: halves gather bytes in pass1.
//   - pass1 stages A via global_load_lds (16B) with pre-swizzled per-lane
//     global source (LDS dest linear), removing VGPR round-trip + cvt VALU.
//   - k_rank2 folded into k_count (rankl = arrival order, cnt from 0).
//   - pass2: one wave per out row (lane = channel), coalesced 128B/rule reads,
//     no intra-wave divergence from segment lengths.
// Tiers: FULL (xb+sort) -> MID (f32 gather + sort) -> atomic fallback.

typedef __bf16 bf16x8_t __attribute__((ext_vector_type(8)));
typedef __bf16 bf16x2_t __attribute__((ext_vector_type(2)));
typedef float f32x4_t __attribute__((ext_vector_type(4)));

#define KOFF 27
#define RULES 50000
#define KR (KOFF * RULES) /* 1,350,000 */
#define CIN 64
#define COUT 64
#define NIN 150000
#define NOUT 150000
#define BR 256
#define BPK ((RULES + BR - 1) / BR) /* 196 */

// ws layout (bytes, 256-aligned)
#define OFF_OFF 0ull          /* int off[NOUT+1] */
#define OFF_BSUM 600064ull    /* int bsum[147] */
#define OFF_RANK 600832ull    /* int rankl[KR] */
#define OFF_XB 6000896ull     /* bf16 xb[NIN][64] */
#define OFF_VALS_FULL 25200896ull /* bf16 vals[KR][64] */
#define OFF_VALS_MID 6000896ull   /* vals when no xb */
#define WS_FULL (25200896ull + 172800000ull) /* 198.0 MB */
#define WS_MID (6000896ull + 172800000ull)   /* 178.8 MB */

__device__ __forceinline__ void gload_lds16(const void* g, void* l) {
  __builtin_amdgcn_global_load_lds(
      (const __attribute__((address_space(1))) unsigned int*)g,
      (__attribute__((address_space(3))) unsigned int*)l, 16, 0, 0);
}

// ---------------- x -> bf16 ----------------
__global__ __launch_bounds__(256) void k_cvt(const float* __restrict__ x,
                                             __bf16* __restrict__ xb) {
  const int i = blockIdx.x * 256 + threadIdx.x;  // one per 8 elems
  if (i < NIN * CIN / 8) {
    const float4 f0 = reinterpret_cast<const float4*>(x)[i * 2];
    const float4 f1 = reinterpret_cast<const float4*>(x)[i * 2 + 1];
    bf16x8_t v;
    v[0] = (__bf16)f0.x; v[1] = (__bf16)f0.y; v[2] = (__bf16)f0.z; v[3] = (__bf16)f0.w;
    v[4] = (__bf16)f1.x; v[5] = (__bf16)f1.y; v[6] = (__bf16)f1.z; v[7] = (__bf16)f1.w;
    reinterpret_cast<bf16x8_t*>(xb)[i] = v;
  }
}

// ---------------- sort kernels ----------------
__global__ __launch_bounds__(256) void k_zero(int* __restrict__ cnt) {
  const int i = blockIdx.x * 256 + threadIdx.x;
  if (i < NOUT) cnt[i] = 0;
}

// counts AND per-rule arrival rank (coalesced write)
__global__ __launch_bounds__(256) void k_count(const int* __restrict__ out_idx,
                                               int* __restrict__ cnt,
                                               int* __restrict__ rankl) {
  const int i = blockIdx.x * 256 + threadIdx.x;
  if (i < KR) rankl[i] = atomicAdd(&cnt[out_idx[i]], 1);
}

__global__ __launch_bounds__(1024) void k_scan1(int* __restrict__ off,
                                                int* __restrict__ bsum) {
  __shared__ int s[1024];
  const int t = threadIdx.x;
  const int i = blockIdx.x * 1024 + t;
  const int v = (i < NOUT) ? off[i] : 0;
  s[t] = v;
  __syncthreads();
#pragma unroll
  for (int d = 1; d < 1024; d <<= 1) {
    const int u = (t >= d) ? s[t - d] : 0;
    __syncthreads();
    s[t] += u;
    __syncthreads();
  }
  if (i < NOUT) off[i] = s[t] - v;  // exclusive within block
  if (t == 1023) bsum[blockIdx.x] = s[1023];
}

__global__ __launch_bounds__(256) void k_scan2(int* __restrict__ bsum, int nb) {
  __shared__ int s[256];
  const int t = threadIdx.x;
  const int v = (t < nb) ? bsum[t] : 0;
  s[t] = v;
  __syncthreads();
#pragma unroll
  for (int d = 1; d < 256; d <<= 1) {
    const int u = (t >= d) ? s[t - d] : 0;
    __syncthreads();
    s[t] += u;
    __syncthreads();
  }
  if (t < nb) bsum[t] = s[t] - v;
}

__global__ __launch_bounds__(256) void k_scan3(int* __restrict__ off,
                                               const int* __restrict__ bsum) {
  const int i = blockIdx.x * 256 + threadIdx.x;
  if (i < NOUT) off[i] += bsum[i >> 10];
  if (i == 0) off[NOUT] = KR;
}

// ---------------- pass 1 (FULL): bf16 gather via global_load_lds ----------------
__global__ __launch_bounds__(256) void pass1_bf16(
    const __bf16* __restrict__ xb, const float* __restrict__ w,
    const int* __restrict__ in_idx, const int* __restrict__ out_idx,
    const int* __restrict__ off_arr, const int* __restrict__ rankl,
    __bf16* __restrict__ vals) {
  __shared__ char lds[256 * 128 + 64 * 128];
  char* const Abase = lds;
  char* const Bbase = lds + 256 * 128;

  const int bid = blockIdx.x;
  const int k = bid / BPK;
  const int rblk = bid - k * BPK;
  const int rule0 = rblk * BR;
  const int t = threadIdx.x;
  const int wid = t >> 6;
  const int lane = t & 63;

  // stage A: per-lane pre-swizzled source, linear LDS dest (m173 pattern).
  // dest byte = rbase*128 + lane*16 -> row r = rbase + (lane>>3), within-row
  // byte (lane&7)*16; fragment reads expect chunk (B>>4)^(r&7) there.
  {
    const int rowInWave = lane >> 3;
    const int srcChunk = (lane & 7) ^ rowInWave;
    const int* idxBase = in_idx + (size_t)k * RULES;
#pragma unroll
    for (int it = 0; it < 8; ++it) {
      const int rbase = it * 32 + wid * 8;
      int rule = rule0 + rbase + rowInWave;
      if (rule > RULES - 1) rule = RULES - 1;  // clamp: finite data, skipped later
      const int src = idxBase[rule];
      const __bf16* gp = xb + ((size_t)src << 6) + (srcChunk << 3);
      gload_lds16(gp, Abase + rbase * 128 + lane * 16);
    }
  }

  // stage B: W_k^T -> LDS[o][c] bf16, swizzled
  {
    const int c = t >> 2;
    const int o0 = (t & 3) * 16;
    const float* wp = w + ((size_t)k * CIN + c) * COUT + o0;
#pragma unroll
    for (int j4 = 0; j4 < 4; ++j4) {
      const float4 f = *reinterpret_cast<const float4*>(wp + j4 * 4);
#pragma unroll
      for (int e = 0; e < 4; ++e) {
        const int o = o0 + j4 * 4 + e;
        const float val = (e == 0) ? f.x : (e == 1) ? f.y : (e == 2) ? f.z : f.w;
        const int addr = o * 128 + ((c * 2) ^ ((o & 7) << 4));
        *reinterpret_cast<__bf16*>(Bbase + addr) = (__bf16)val;
      }
    }
  }

  __syncthreads();

  const int rA = lane & 15;
  const int g = lane >> 4;

  bf16x8_t af[4][2];
  bf16x8_t bfr[4][2];
#pragma unroll
  for (int m = 0; m < 4; ++m)
#pragma unroll
    for (int kk = 0; kk < 2; ++kk) {
      const int r = wid * 64 + m * 16 + rA;
      const int colByte = (kk * 64 + g * 16) ^ ((r & 7) << 4);
      af[m][kk] = *reinterpret_cast<const bf16x8_t*>(Abase + r * 128 + colByte);
    }
#pragma unroll
  for (int n = 0; n < 4; ++n)
#pragma unroll
    for (int kk = 0; kk < 2; ++kk) {
      const int o = n * 16 + rA;
      const int colByte = (kk * 64 + g * 16) ^ ((o & 7) << 4);
      bfr[n][kk] = *reinterpret_cast<const bf16x8_t*>(Bbase + o * 128 + colByte);
    }

  __syncthreads();  // frag reads done; Abase reused for D staging

  f32x4_t acc[4][4];
#pragma unroll
  for (int m = 0; m < 4; ++m)
#pragma unroll
    for (int n = 0; n < 4; ++n)
#pragma unroll
      for (int e = 0; e < 4; ++e) acc[m][n][e] = 0.0f;

#pragma unroll
  for (int kk = 0; kk < 2; ++kk)
#pragma unroll
    for (int m = 0; m < 4; ++m)
#pragma unroll
      for (int n = 0; n < 4; ++n)
        acc[m][n] = __builtin_amdgcn_mfma_f32_16x16x32_bf16(
            af[m][kk], bfr[n][kk], acc[m][n], 0, 0, 0);

  // stage D -> LDS bf16 rows (swizzled)
  const bool evenLane = (rA & 1) == 0;
#pragma unroll
  for (int m = 0; m < 4; ++m) {
#pragma unroll
    for (int j = 0; j < 4; ++j) {
      const int rr = wid * 64 + m * 16 + g * 4 + j;
      float mine[4], other[4];
#pragma unroll
      for (int n = 0; n < 4; ++n) {
        mine[n] = acc[m][n][j];
        other[n] = __shfl_xor(mine[n], 1, 64);
      }
      const int swz = (rr & 7) << 4;
      if (evenLane) {
#pragma unroll
        for (int n = 0; n < 2; ++n) {
          bf16x2_t p; p[0] = (__bf16)mine[n]; p[1] = (__bf16)other[n];
          const int col = n * 16 + rA;
          *reinterpret_cast<bf16x2_t*>(Abase + rr * 128 + ((col * 2) ^ swz)) = p;
        }
      } else {
#pragma unroll
        for (int n = 2; n < 4; ++n) {
          bf16x2_t p; p[0] = (__bf16)other[n]; p[1] = (__bf16)mine[n];
          const int col = n * 16 + rA - 1;
          *reinterpret_cast<bf16x2_t*>(Abase + rr * 128 + ((col * 2) ^ swz)) = p;
        }
      }
    }
  }

  __syncthreads();

  // writeback: scatter full 128B rows to vals[off[o] + rankl[rule]]
  {
    const int chunk = t & 7;
    const int r0 = t >> 3;
#pragma unroll
    for (int pass = 0; pass < 8; ++pass) {
      const int r = r0 + pass * 32;
      const int rule = rule0 + r;
      if (rule < RULES) {
        const size_t gi = (size_t)k * RULES + rule;
        const int dst = off_arr[out_idx[gi]] + rankl[gi];
        const bf16x8_t v = *reinterpret_cast<const bf16x8_t*>(
            Abase + r * 128 + ((chunk * 16) ^ ((r & 7) << 4)));
        *reinterpret_cast<bf16x8_t*>(vals + (size_t)dst * COUT + chunk * 8) = v;
      }
    }
  }
}

// ---------------- pass 1 (MID): f32 gather, no xb ----------------
__global__ __launch_bounds__(256) void pass1_f32(
    const float* __restrict__ x, const float* __restrict__ w,
    const int* __restrict__ in_idx, const int* __restrict__ out_idx,
    const int* __restrict__ off_arr, const int* __restrict__ rankl,
    __bf16* __restrict__ vals) {
  __shared__ char lds[256 * 128 + 64 * 128];
  char* const Abase = lds;
  char* const Bbase = lds + 256 * 128;

  const int bid = blockIdx.x;
  const int k = bid / BPK;
  const int rblk = bid - k * BPK;
  const int rule0 = rblk * BR;
  const int t = threadIdx.x;

  {
    const int chunk = t & 7;
    const int r0 = t >> 3;
#pragma unroll
    for (int pass = 0; pass < 8; ++pass) {
      const int r = r0 + pass * 32;
      const int rule = rule0 + r;
      bf16x8_t v;
      if (rule < RULES) {
        const int src = in_idx[(size_t)k * RULES + rule];
        const float* p = x + (size_t)src * CIN + chunk * 8;
        const float4 f0 = *reinterpret_cast<const float4*>(p);
        const float4 f1 = *reinterpret_cast<const float4*>(p + 4);
        v[0] = (__bf16)f0.x; v[1] = (__bf16)f0.y;
        v[2] = (__bf16)f0.z; v[3] = (__bf16)f0.w;
        v[4] = (__bf16)f1.x; v[5] = (__bf16)f1.y;
        v[6] = (__bf16)f1.z; v[7] = (__bf16)f1.w;
      } else {
#pragma unroll
        for (int e = 0; e < 8; ++e) v[e] = (__bf16)0.0f;
      }
      const int colByte = (chunk * 16) ^ ((r & 7) << 4);
      *reinterpret_cast<bf16x8_t*>(Abase + r * 128 + colByte) = v;
    }
  }
  {
    const int c = t >> 2;
    const int o0 = (t & 3) * 16;
    const float* wp = w + ((size_t)k * CIN + c) * COUT + o0;
#pragma unroll
    for (int j4 = 0; j4 < 4; ++j4) {
      const float4 f = *reinterpret_cast<const float4*>(wp + j4 * 4);
#pragma unroll
      for (int e = 0; e < 4; ++e) {
        const int o = o0 + j4 * 4 + e;
        const float val = (e == 0) ? f.x : (e == 1) ? f.y : (e == 2) ? f.z : f.w;
        const int addr = o * 128 + ((c * 2) ^ ((o & 7) << 4));
        *reinterpret_cast<__bf16*>(Bbase + addr) = (__bf16)val;
      }
    }
  }
  __syncthreads();

  const int wid = t >> 6;
  const int l = t & 63;
  const int rA = l & 15;
  const int g = l >> 4;

  bf16x8_t af[4][2];
  bf16x8_t bfr[4][2];
#pragma unroll
  for (int m = 0; m < 4; ++m)
#pragma unroll
    for (int kk = 0; kk < 2; ++kk) {
      const int r = wid * 64 + m * 16 + rA;
      const int colByte = (kk * 64 + g * 16) ^ ((r & 7) << 4);
      af[m][kk] = *reinterpret_cast<const bf16x8_t*>(Abase + r * 128 + colByte);
    }
#pragma unroll
  for (int n = 0; n < 4; ++n)
#pragma unroll
    for (int kk = 0; kk < 2; ++kk) {
      const int o = n * 16 + rA;
      const int colByte = (kk * 64 + g * 16) ^ ((o & 7) << 4);
      bfr[n][kk] = *reinterpret_cast<const bf16x8_t*>(Bbase + o * 128 + colByte);
    }

  __syncthreads();

  f32x4_t acc[4][4];
#pragma unroll
  for (int m = 0; m < 4; ++m)
#pragma unroll
    for (int n = 0; n < 4; ++n)
#pragma unroll
      for (int e = 0; e < 4; ++e) acc[m][n][e] = 0.0f;

#pragma unroll
  for (int kk = 0; kk < 2; ++kk)
#pragma unroll
    for (int m = 0; m < 4; ++m)
#pragma unroll
      for (int n = 0; n < 4; ++n)
        acc[m][n] = __builtin_amdgcn_mfma_f32_16x16x32_bf16(
            af[m][kk], bfr[n][kk], acc[m][n], 0, 0, 0);

  const bool evenLane = (rA & 1) == 0;
#pragma unroll
  for (int m = 0; m < 4; ++m) {
#pragma unroll
    for (int j = 0; j < 4; ++j) {
      const int rr = wid * 64 + m * 16 + g * 4 + j;
      float mine[4], other[4];
#pragma unroll
      for (int n = 0; n < 4; ++n) {
        mine[n] = acc[m][n][j];
        other[n] = __shfl_xor(mine[n], 1, 64);
      }
      const int swz = (rr & 7) << 4;
      if (evenLane) {
#pragma unroll
        for (int n = 0; n < 2; ++n) {
          bf16x2_t p; p[0] = (__bf16)mine[n]; p[1] = (__bf16)other[n];
          const int col = n * 16 + rA;
          *reinterpret_cast<bf16x2_t*>(Abase + rr * 128 + ((col * 2) ^ swz)) = p;
        }
      } else {
#pragma unroll
        for (int n = 2; n < 4; ++n) {
          bf16x2_t p; p[0] = (__bf16)other[n]; p[1] = (__bf16)mine[n];
          const int col = n * 16 + rA - 1;
          *reinterpret_cast<bf16x2_t*>(Abase + rr * 128 + ((col * 2) ^ swz)) = p;
        }
      }
    }
  }

  __syncthreads();

  {
    const int chunk = t & 7;
    const int r0 = t >> 3;
#pragma unroll
    for (int pass = 0; pass < 8; ++pass) {
      const int r = r0 + pass * 32;
      const int rule = rule0 + r;
      if (rule < RULES) {
        const size_t gi = (size_t)k * RULES + rule;
        const int dst = off_arr[out_idx[gi]] + rankl[gi];
        const bf16x8_t v = *reinterpret_cast<const bf16x8_t*>(
            Abase + r * 128 + ((chunk * 16) ^ ((r & 7) << 4)));
        *reinterpret_cast<bf16x8_t*>(vals + (size_t)dst * COUT + chunk * 8) = v;
      }
    }
  }
}

// ---------------- pass 2: wave-per-row streaming reduce ----------------
__global__ __launch_bounds__(256) void pass2_kernel(
    const __bf16* __restrict__ vals, const int* __restrict__ off,
    const float* __restrict__ bias, float* __restrict__ out) {
  const int lane = threadIdx.x & 63;
  const int o = blockIdx.x * 4 + (threadIdx.x >> 6);
  if (o >= NOUT) return;

  float acc = bias[lane];
  const int r0 = off[o];
  const int r1 = off[o + 1];
  const __bf16* vp = vals + (size_t)r0 * COUT + lane;
  for (int j = r0; j < r1; ++j, vp += COUT) acc += (float)*vp;
  out[(size_t)o * COUT + lane] = acc;
}

// ---------------- fallback (tiny ws): atomic scatter ----------------
__global__ __launch_bounds__(256) void init_out_kernel(
    const float* __restrict__ bias, float* __restrict__ out, int total4) {
  const int i = blockIdx.x * blockDim.x + threadIdx.x;
  if (i < total4) {
    const float4 v = reinterpret_cast<const float4*>(bias)[i & 15];
    reinterpret_cast<float4*>(out)[i] = v;
  }
}

__global__ __launch_bounds__(256) void spconv_atomic_kernel(
    const float* __restrict__ x, const float* __restrict__ w,
    const int* __restrict__ in_idx, const int* __restrict__ out_idx,
    float* __restrict__ out) {
  __shared__ char lds[256 * 128 + 64 * 128];
  char* const Abase = lds;
  char* const Bbase = lds + 256 * 128;

  const int bid = blockIdx.x;
  const int k = bid / BPK;
  const int rblk = bid - k * BPK;
  const int rule0 = rblk * BR;
  const int t = threadIdx.x;

  {
    const int chunk = t & 7;
    const int r0 = t >> 3;
#pragma unroll
    for (int pass = 0; pass < 8; ++pass) {
      const int r = r0 + pass * 32;
      const int rule = rule0 + r;
      bf16x8_t v;
      if (rule < RULES) {
        const int src = in_idx[(size_t)k * RULES + rule];
        const float* p = x + (size_t)src * CIN + chunk * 8;
        const float4 f0 = *reinterpret_cast<const float4*>(p);
        const float4 f1 = *reinterpret_cast<const float4*>(p + 4);
        v[0] = (__bf16)f0.x; v[1] = (__bf16)f0.y;
        v[2] = (__bf16)f0.z; v[3] = (__bf16)f0.w;
        v[4] = (__bf16)f1.x; v[5] = (__bf16)f1.y;
        v[6] = (__bf16)f1.z; v[7] = (__bf16)f1.w;
      } else {
#pragma unroll
        for (int e = 0; e < 8; ++e) v[e] = (__bf16)0.0f;
      }
      const int colByte = (chunk * 16) ^ ((r & 7) << 4);
      *reinterpret_cast<bf16x8_t*>(Abase + r * 128 + colByte) = v;
    }
  }
  {
    const int c = t >> 2;
    const int o0 = (t & 3) * 16;
    const float* wp = w + ((size_t)k * CIN + c) * COUT + o0;
#pragma unroll
    for (int j4 = 0; j4 < 4; ++j4) {
      const float4 f = *reinterpret_cast<const float4*>(wp + j4 * 4);
#pragma unroll
      for (int e = 0; e < 4; ++e) {
        const int o = o0 + j4 * 4 + e;
        const float val = (e == 0) ? f.x : (e == 1) ? f.y : (e == 2) ? f.z : f.w;
        const int addr = o * 128 + ((c * 2) ^ ((o & 7) << 4));
        *reinterpret_cast<__bf16*>(Bbase + addr) = (__bf16)val;
      }
    }
  }
  __syncthreads();

  const int wid = t >> 6;
  const int l = t & 63;
  const int rA = l & 15;
  const int g = l >> 4;

  bf16x8_t af[4][2];
  bf16x8_t bfr[4][2];
#pragma unroll
  for (int m = 0; m < 4; ++m)
#pragma unroll
    for (int kk = 0; kk < 2; ++kk) {
      const int r = wid * 64 + m * 16 + rA;
      const int colByte = (kk * 64 + g * 16) ^ ((r & 7) << 4);
      af[m][kk] = *reinterpret_cast<const bf16x8_t*>(Abase + r * 128 + colByte);
    }
#pragma unroll
  for (int n = 0; n < 4; ++n)
#pragma unroll
    for (int kk = 0; kk < 2; ++kk) {
      const int o = n * 16 + rA;
      const int colByte = (kk * 64 + g * 16) ^ ((o & 7) << 4);
      bfr[n][kk] = *reinterpret_cast<const bf16x8_t*>(Bbase + o * 128 + colByte);
    }

  f32x4_t acc[4][4];
#pragma unroll
  for (int m = 0; m < 4; ++m)
#pragma unroll
    for (int n = 0; n < 4; ++n)
#pragma unroll
      for (int e = 0; e < 4; ++e) acc[m][n][e] = 0.0f;

#pragma unroll
  for (int kk = 0; kk < 2; ++kk)
#pragma unroll
    for (int m = 0; m < 4; ++m)
#pragma unroll
      for (int n = 0; n < 4; ++n)
        acc[m][n] = __builtin_amdgcn_mfma_f32_16x16x32_bf16(
            af[m][kk], bfr[n][kk], acc[m][n], 0, 0, 0);

#pragma unroll
  for (int m = 0; m < 4; ++m)
#pragma unroll
    for (int j = 0; j < 4; ++j) {
      const int rr = wid * 64 + m * 16 + g * 4 + j;
      const int rule = rule0 + rr;
      if (rule < RULES) {
        const int orow = out_idx[(size_t)k * RULES + rule];
        float* op = out + (size_t)orow * COUT + rA;
#pragma unroll
        for (int n = 0; n < 4; ++n) atomicAdd(op + n * 16, acc[m][n][j]);
      }
    }
}

// ---------------- launch ----------------
extern "C" void kernel_launch(void* const* d_in, const int* in_sizes, int n_in,
                              void* d_out, int out_size, void* d_ws, size_t ws_size,
                              hipStream_t stream) {
  const float* x = (const float*)d_in[0];
  const float* w = (const float*)d_in[1];
  const float* bias = (const float*)d_in[2];
  const int* in_idx = (const int*)d_in[3];
  const int* out_idx = (const int*)d_in[4];
  float* out = (float*)d_out;

  if (ws_size >= WS_MID) {
    char* ws = (char*)d_ws;
    int* off = (int*)(ws + OFF_OFF);
    int* bsum = (int*)(ws + OFF_BSUM);
    int* rankl = (int*)(ws + OFF_RANK);
    const bool full = (ws_size >= WS_FULL);
    __bf16* xb = (__bf16*)(ws + OFF_XB);
    __bf16* vals = (__bf16*)(ws + (full ? OFF_VALS_FULL : OFF_VALS_MID));

    const int nb1 = (NOUT + 1023) / 1024;  // 147
    if (full) k_cvt<<<(NIN * CIN / 8 + 255) / 256, 256, 0, stream>>>(x, xb);
    k_zero<<<(NOUT + 255) / 256, 256, 0, stream>>>(off);
    k_count<<<(KR + 255) / 256, 256, 0, stream>>>(out_idx, off, rankl);
    k_scan1<<<nb1, 1024, 0, stream>>>(off, bsum);
    k_scan2<<<1, 256, 0, stream>>>(bsum, nb1);
    k_scan3<<<(NOUT + 255) / 256, 256, 0, stream>>>(off, bsum);
    if (full) {
      pass1_bf16<<<KOFF * BPK, 256, 0, stream>>>(xb, w, in_idx, out_idx, off,
                                                 rankl, vals);
    } else {
      pass1_f32<<<KOFF * BPK, 256, 0, stream>>>(x, w, in_idx, out_idx, off,
                                                rankl, vals);
    }
    pass2_kernel<<<(NOUT + 3) / 4, 256, 0, stream>>>(vals, off, bias, out);
  } else {
    const int total4 = NOUT * COUT / 4;
    init_out_kernel<<<(total4 + 255) / 256, 256, 0, stream>>>(bias, out, total4);
    spconv_atomic_kernel<<<KOFF * BPK, 256, 0, stream>>>(x, w, in_idx, out_idx, out);
  }
}